// Round 10
// baseline (734.889 us; speedup 1.0000x reference)
//
#include <hip/hip_runtime.h>
#include <hip/hip_cooperative_groups.h>
#include <math.h>

#define NV 32000
#define NE 1024
#define NH 1024
#define NS 1024
#define NB 64

typedef __attribute__((ext_vector_type(4))) float f32x4;
typedef __attribute__((ext_vector_type(8))) short bf16x8;

// d_out layout (floats): output(B,V) | context(B,H) | hidden(1,B,H) | attn(B,1,S)
#define OUT_CTX   (NB*NV)
#define OUT_HID   (NB*NV + NB*NH)
#define OUT_ATTN  (NB*NV + 2*NB*NH)

// workspace layout (float offsets)
#define WS_XA   0                          // ushort[64][2048] x0 bf16, FRAGMENT-ORDERED
#define WS_HA   (WS_XA + 65536)            // ushort[64][1024] h_prev bf16, FRAGMENT-ORDERED
#define WS_PG   (WS_HA + 32768)            // f32 [12][3072][64] GRU partials
#define WS_E    (WS_PG + 12*3072*64)       // f32 [64][1024] raw energies
#define WS_PCTX (WS_E + NB*NS)             // f32 [64][64][1024] attn ctx partials (b, g, h)
#define WS_ML   (WS_PCTX + 64*64*1024)     // f32 [64][64][2]  (m, l) per (b, g)
#define WS_LA   (WS_ML + 8192)             // ushort[64][2048] concat(h,ctx) bf16, FRAGMENT-ORDERED
#define WS_ML2  (WS_LA + 65536)            // f32 [64][2048][2] logits chunk (m,l) per (row, vt)
#define WS_LSE  (WS_ML2 + 64*2048*2)       // f32 [64] lse per row
#define WS_P    (WS_LSE + 64)              // f32 [2000][1024] logits h-half partials, tile-blocked

// fragment-ordered offset (in shorts) for a [64][K] bf16 activation matrix:
// off(row,k) = ((k>>5)*4 + ((k>>3)&3))*512 + row*8 + (k&7)

__device__ inline unsigned short f2bf(float f) {
    unsigned u = __builtin_bit_cast(unsigned, f);
    u += 0x7fffu + ((u >> 16) & 1u);   // RNE
    return (unsigned short)(u >> 16);
}

__device__ inline bf16x8 cvt8(float4 a, float4 b) {
    bf16x8 r;
    r[0] = (short)f2bf(a.x); r[1] = (short)f2bf(a.y);
    r[2] = (short)f2bf(a.z); r[3] = (short)f2bf(a.w);
    r[4] = (short)f2bf(b.x); r[5] = (short)f2bf(b.y);
    r[6] = (short)f2bf(b.z); r[7] = (short)f2bf(b.w);
    return r;
}

__device__ inline void store_bf4(unsigned short* p, float4 v) {
    ushort4 u = make_ushort4(f2bf(v.x), f2bf(v.y), f2bf(v.z), f2bf(v.w));
    *(ushort4*)p = u;
}

// ================= phase bodies (verbatim from r8/r9 kernels) =================

__device__ __forceinline__ void prep_body(int b, int t, const int* wi, const float* lctx,
                                          const float* lhid, const float* emb, float* ws) {
    unsigned short* XA = (unsigned short*)(ws + WS_XA);
    unsigned short* HA = (unsigned short*)(ws + WS_HA);
    long row = wi[b];
    float4 e4 = ((const float4*)(emb + row*NE))[t];
    float4 c4 = ((const float4*)(lctx + (long)b*NH))[t];
    float4 h4 = ((const float4*)(lhid + (long)b*NH))[t];
    int o1 = ((t>>3)*4 + ((t>>1)&3))*512 + b*8 + 4*(t&1);
    int o2 = ((32 + (t>>3))*4 + ((t>>1)&3))*512 + b*8 + 4*(t&1);
    store_bf4(XA + o1, e4);
    store_bf4(XA + o2, c4);
    store_bf4(HA + o1, h4);
}

__device__ __forceinline__ void gru_body(int wave, int lane, const float* w_ih,
                                         const float* w_hh, float* ws) {
    int c = wave % 12, ntile = wave / 12;           // 192 n-tiles
    int n0 = ntile * 16;
    int col = lane & 15, kg = lane >> 4;
    const unsigned short* XA = (const unsigned short*)(ws + WS_XA);
    const unsigned short* HA = (const unsigned short*)(ws + WS_HA);
    const float* Wp; const unsigned short* Af; int ld, kbase;
    if (c < 8) { Wp = w_ih; Af = XA; ld = 2048; kbase = c*256; }
    else       { Wp = w_hh; Af = HA; ld = 1024; kbase = (c-8)*256; }
    const float* wrow = Wp + (long)(n0 + col)*ld + kbase + kg*8;
    const unsigned short* ap = Af + (kbase>>5)*2048 + kg*512 + col*8;
    f32x4 acc[4];
    #pragma unroll
    for (int m = 0; m < 4; m++) acc[m] = (f32x4){0.f,0.f,0.f,0.f};
    #pragma unroll 4
    for (int k0 = 0; k0 < 256; k0 += 32) {
        float4 wa = *(const float4*)(wrow + k0);
        float4 wb = *(const float4*)(wrow + k0 + 4);
        bf16x8 bfv = cvt8(wa, wb);
        const unsigned short* a0 = ap + (k0>>5)*2048;
        #pragma unroll
        for (int m = 0; m < 4; m++) {
            bf16x8 af = *(const bf16x8*)(a0 + m*128);
            acc[m] = __builtin_amdgcn_mfma_f32_16x16x32_bf16(af, bfv, acc[m], 0, 0, 0);
        }
    }
    float* pg = ws + WS_PG + ((long)c*3072 + n0 + col)*64;
    #pragma unroll
    for (int m = 0; m < 4; m++)
        #pragma unroll
        for (int j = 0; j < 4; j++)
            pg[m*16 + kg*4 + j] = acc[m][j];
}

__device__ __forceinline__ void gates_body(int g, const float* wsc, const float* b_ih,
                                           const float* b_hh, const float* lhid,
                                           float* out, float* ws) {
    int b = g & 63, i = g >> 6;
    float gir=0.f, giz=0.f, gin=0.f, ghr=0.f, ghz=0.f, ghn=0.f;
    #pragma unroll
    for (int c = 0; c < 8; c++) {
        long base = WS_PG + (long)c*3072*64;
        gir += wsc[base + ((long)(0*NH + i))*64 + b];
        giz += wsc[base + ((long)(1*NH + i))*64 + b];
        gin += wsc[base + ((long)(2*NH + i))*64 + b];
    }
    #pragma unroll
    for (int c = 8; c < 12; c++) {
        long base = WS_PG + (long)c*3072*64;
        ghr += wsc[base + ((long)(0*NH + i))*64 + b];
        ghz += wsc[base + ((long)(1*NH + i))*64 + b];
        ghn += wsc[base + ((long)(2*NH + i))*64 + b];
    }
    gir += b_ih[i];        ghr += b_hh[i];
    giz += b_ih[NH + i];   ghz += b_hh[NH + i];
    gin += b_ih[2*NH + i]; ghn += b_hh[2*NH + i];
    float r = 1.f / (1.f + expf(-(gir + ghr)));
    float z = 1.f / (1.f + expf(-(giz + ghz)));
    float n = tanhf(gin + r*ghn);
    float hp = lhid[(long)b*NH + i];
    float h = (1.f - z)*n + z*hp;
    out[OUT_HID + (long)b*NH + i] = h;
    ((unsigned short*)(ws + WS_LA))[((i>>5)*4 + ((i>>3)&3))*512 + b*8 + (i&7)] = f2bf(h);
}

__device__ __forceinline__ void logh_body(int vt, int lane, const float* oW, float* ws) {
    int v0 = vt * 16;
    int col = lane & 15, kg = lane >> 4;
    const unsigned short* LA = (const unsigned short*)(ws + WS_LA);
    const float* wrow = oW + (long)(v0 + col)*2048 + kg*8;
    const unsigned short* ap = LA + kg*512 + col*8;
    f32x4 acc[4];
    #pragma unroll
    for (int m = 0; m < 4; m++) acc[m] = (f32x4){0.f,0.f,0.f,0.f};
    #pragma unroll 4
    for (int k0 = 0; k0 < 1024; k0 += 32) {
        float4 wa = *(const float4*)(wrow + k0);
        float4 wb = *(const float4*)(wrow + k0 + 4);
        bf16x8 bfv = cvt8(wa, wb);
        const unsigned short* a0 = ap + (k0>>5)*2048;
        #pragma unroll
        for (int m = 0; m < 4; m++) {
            bf16x8 af = *(const bf16x8*)(a0 + m*128);
            acc[m] = __builtin_amdgcn_mfma_f32_16x16x32_bf16(af, bfv, acc[m], 0, 0, 0);
        }
    }
    float* P = ws + WS_P + (long)vt*1024;
    #pragma unroll
    for (int m = 0; m < 4; m++)
        #pragma unroll
        for (int j = 0; j < 4; j++)
            P[(m*16 + kg*4 + j)*16 + col] = acc[m][j];
}

__device__ __forceinline__ void attn_body(int b, int g, int lane, const float* enc,
                                          const float* out, float* ws) {
    const float4* hr = (const float4*)(out + OUT_HID + (long)b*NH);
    float4 h0 = hr[lane], h1 = hr[64+lane], h2 = hr[128+lane], h3 = hr[192+lane];
    float m = -1e30f, l = 0.f;
    float4 c0 = make_float4(0,0,0,0), c1 = c0, c2 = c0, c3 = c0;
    const float4* vp = (const float4*)(enc + ((long)(g*16)*NB + b)*NH);
    const long sstr = (long)NB*NH/4;         // float4 stride between s
    float4 a0 = vp[lane], a1 = vp[64+lane], a2 = vp[128+lane], a3 = vp[192+lane];
    #pragma unroll
    for (int si = 0; si < 16; si++) {
        float4 n0 = a0, n1 = a1, n2 = a2, n3 = a3;
        if (si < 15) {
            const float4* np = vp + (long)(si+1)*sstr;
            n0 = np[lane]; n1 = np[64+lane]; n2 = np[128+lane]; n3 = np[192+lane];
        }
        float d = a0.x*h0.x + a0.y*h0.y + a0.z*h0.z + a0.w*h0.w
                + a1.x*h1.x + a1.y*h1.y + a1.z*h1.z + a1.w*h1.w
                + a2.x*h2.x + a2.y*h2.y + a2.z*h2.z + a2.w*h2.w
                + a3.x*h3.x + a3.y*h3.y + a3.z*h3.z + a3.w*h3.w;
        #pragma unroll
        for (int o = 32; o > 0; o >>= 1) d += __shfl_xor(d, o);
        if (lane == 0) ws[WS_E + (long)b*NS + g*16 + si] = d;
        // defer-max: rescale only when d exceeds running max by > 8 (wave-uniform branch)
        if (d > m + 8.f) {
            float coef = expf(m - d);       // m=-1e30 first time -> coef = 0
            l *= coef;
            c0.x *= coef; c0.y *= coef; c0.z *= coef; c0.w *= coef;
            c1.x *= coef; c1.y *= coef; c1.z *= coef; c1.w *= coef;
            c2.x *= coef; c2.y *= coef; c2.z *= coef; c2.w *= coef;
            c3.x *= coef; c3.y *= coef; c3.z *= coef; c3.w *= coef;
            m = d;
        }
        float p = expf(d - m);               // bounded by e^8
        l += p;
        c0.x += p*a0.x; c0.y += p*a0.y; c0.z += p*a0.z; c0.w += p*a0.w;
        c1.x += p*a1.x; c1.y += p*a1.y; c1.z += p*a1.z; c1.w += p*a1.w;
        c2.x += p*a2.x; c2.y += p*a2.y; c2.z += p*a2.z; c2.w += p*a2.w;
        c3.x += p*a3.x; c3.y += p*a3.y; c3.z += p*a3.z; c3.w += p*a3.w;
        a0 = n0; a1 = n1; a2 = n2; a3 = n3;
    }
    float* pc = ws + WS_PCTX + ((long)b*64 + g)*1024;
    *(float4*)(pc + 0*256 + lane*4) = c0;
    *(float4*)(pc + 1*256 + lane*4) = c1;
    *(float4*)(pc + 2*256 + lane*4) = c2;
    *(float4*)(pc + 3*256 + lane*4) = c3;
    if (lane == 0) {
        ws[WS_ML + ((long)b*64 + g)*2]     = m;
        ws[WS_ML + ((long)b*64 + g)*2 + 1] = l;
    }
}

__device__ __forceinline__ void reduce_body(int b, int q, int t, float* sm, float* sl,
                                            float* sc, float* sMg, const float* wsc,
                                            float* out, float* ws) {
    if (t < 64) {
        sm[t] = wsc[WS_ML + ((long)b*64 + t)*2];
        sl[t] = wsc[WS_ML + ((long)b*64 + t)*2 + 1];
    }
    __syncthreads();
    if (t == 0) {
        float M = -1e30f;
        for (int g = 0; g < 64; g++) M = fmaxf(M, sm[g]);
        float L = 0.f;
        for (int g = 0; g < 64; g++) L += sl[g]*expf(sm[g] - M);
        sMg[0] = M; sMg[1] = 1.f/L;
    }
    __syncthreads();
    float M = sMg[0], invL = sMg[1];
    if (t < 64) sc[t] = expf(sm[t] - M);
    __syncthreads();
    int h = q*256 + t;
    float acc = 0.f;
    #pragma unroll 8
    for (int g = 0; g < 64; g++)
        acc += sc[g] * wsc[WS_PCTX + ((long)b*64 + g)*1024 + h];
    float ctx = acc * invL;
    out[OUT_CTX + (long)b*NH + h] = ctx;
    int k = 1024 + h;
    ((unsigned short*)(ws + WS_LA))[((k>>5)*4 + ((k>>3)&3))*512 + b*8 + (k&7)] = f2bf(ctx);
    int s = q*256 + t;
    float e = wsc[WS_E + (long)b*NS + s];
    out[OUT_ATTN + (long)b*NS + s] = expf(e - M)*invL;
}

__device__ __forceinline__ void ctx_body(int vt, int lane, const float* oW,
                                         const float* ob, const float* wsc,
                                         float* out, float* ws) {
    int v0 = vt * 16;
    int col = lane & 15, kg = lane >> 4;
    const unsigned short* LA = (const unsigned short*)(wsc + WS_LA);
    const float* wrow = oW + (long)(v0 + col)*2048 + 1024 + kg*8;
    const unsigned short* ap = LA + 32*2048 + kg*512 + col*8;   // k-base 1024
    f32x4 acc[4];
    #pragma unroll
    for (int m = 0; m < 4; m++) acc[m] = (f32x4){0.f,0.f,0.f,0.f};
    #pragma unroll 4
    for (int k0 = 0; k0 < 1024; k0 += 32) {
        float4 wa = *(const float4*)(wrow + k0);
        float4 wb = *(const float4*)(wrow + k0 + 4);
        bf16x8 bfv = cvt8(wa, wb);
        const unsigned short* a0 = ap + (k0>>5)*2048;
        #pragma unroll
        for (int m = 0; m < 4; m++) {
            bf16x8 af = *(const bf16x8*)(a0 + m*128);
            acc[m] = __builtin_amdgcn_mfma_f32_16x16x32_bf16(af, bfv, acc[m], 0, 0, 0);
        }
    }
    const float* P = wsc + WS_P + (long)vt*1024;
    float bias = ob[v0 + col];
    #pragma unroll
    for (int m = 0; m < 4; m++) {
        #pragma unroll
        for (int j = 0; j < 4; j++) {
            int row = m*16 + kg*4 + j;
            float v = acc[m][j] + P[row*16 + col] + bias;
            out[(long)row*NV + v0 + col] = v;
            float mx = v;
            mx = fmaxf(mx, __shfl_xor(mx, 1));
            mx = fmaxf(mx, __shfl_xor(mx, 2));
            mx = fmaxf(mx, __shfl_xor(mx, 4));
            mx = fmaxf(mx, __shfl_xor(mx, 8));
            float p = expf(v - mx);
            p += __shfl_xor(p, 1);
            p += __shfl_xor(p, 2);
            p += __shfl_xor(p, 4);
            p += __shfl_xor(p, 8);
            if (col == 0)
                *(float2*)(ws + WS_ML2 + ((long)row*2048 + vt)*2) = make_float2(mx, p);
        }
    }
}

__device__ __forceinline__ void lsenorm_body(int b, int oct, int t, float* sm_, float* sl_,
                                             const float* wsc, float* out) {
    const float2* ml = (const float2*)(wsc + WS_ML2 + (long)b*4096);
    float m = -1e30f, l = 0.f;
    for (int c = t; c < 2000; c += 256) {
        float2 v = ml[c];
        float mn = fmaxf(m, v.x);
        l = l*expf(m - mn) + v.y*expf(v.x - mn);
        m = mn;
    }
    sm_[t] = m; sl_[t] = l; __syncthreads();
    for (int o = 128; o > 0; o >>= 1) {
        if (t < o) {
            float m2 = sm_[t+o], l2 = sl_[t+o];
            float mn = fmaxf(sm_[t], m2);
            sl_[t] = sl_[t]*expf(sm_[t] - mn) + l2*expf(m2 - mn);
            sm_[t] = mn;
        }
        __syncthreads();
    }
    float lse = sm_[0] + logf(sl_[0]);
    float4* row4 = (float4*)(out + (long)b*NV + oct*4000);
    #pragma unroll
    for (int j = 0; j < 4; j++) {
        int idx = t + j*256;
        if (idx < 1000) {
            float4 v = row4[idx];
            row4[idx] = make_float4(v.x-lse, v.y-lse, v.z-lse, v.w-lse);
        }
    }
}

// ================= cooperative mega-kernel: whole pipeline, 768 blocks =================
__global__ void __launch_bounds__(256, 3)
k_mega(const int* wi, const float* lctx, const float* lhid, const float* enc,
       const float* emb, const float* w_ih, const float* w_hh, const float* b_ih,
       const float* b_hh, const float* oW, const float* ob, float* out, float* ws) {
    cooperative_groups::grid_group grid = cooperative_groups::this_grid();
    int t = threadIdx.x, blk = blockIdx.x;
    int widx = t >> 6, lane = t & 63;
    int wid = blk*4 + widx;                  // 0..3071
    __shared__ float s_a[256], s_b[256], s_c[64], s_m[2];

    // P0: prep
    if (blk < 64) prep_body(blk, t, wi, lctx, lhid, emb, ws);
    grid.sync();
    // P1: GRU GEMM (2304 units)
    if (wid < 2304) gru_body(wid, lane, w_ih, w_hh, ws);
    grid.sync();
    // P2: gates (65536 threads)
    { int gid = blk*256 + t; if (gid < 65536) gates_body(gid, ws, b_ih, b_hh, lhid, out, ws); }
    grid.sync();
    // P3: attention (units 0..4095) + logits h-half (units 4096..6095), 2 passes
    #pragma unroll 1
    for (int p = 0; p < 2; p++) {
        int u = wid + p*3072;
        if (u < 4096)       attn_body(u >> 6, u & 63, lane, enc, out, ws);
        else if (u < 6096)  logh_body(u - 4096, lane, oW, ws);
    }
    grid.sync();
    // P4: attn reduce (256 block-units)
    if (blk < 256) reduce_body(blk >> 2, blk & 3, t, s_a, s_b, s_c, s_m, ws, out, ws);
    grid.sync();
    // P5: logits ctx-half (2000 wave-units)
    if (wid < 2000) ctx_body(wid, lane, oW, ob, ws, out, ws);
    grid.sync();
    // P6: lse + normalize (512 block-units)
    if (blk < 512) lsenorm_body(blk >> 3, blk & 7, t, s_a, s_b, ws, out);
}

// ================= standalone fallback kernels (r8 config) =================
__global__ void k_prep_g(const int* wi, const float* lctx, const float* lhid,
                         const float* emb, float* ws) {
    prep_body(blockIdx.x, threadIdx.x, wi, lctx, lhid, emb, ws);
}
__global__ void __launch_bounds__(256) k_gru_g(const float* w_ih, const float* w_hh, float* ws) {
    gru_body(blockIdx.x*4 + (threadIdx.x >> 6), threadIdx.x & 63, w_ih, w_hh, ws);
}
__global__ void k_gates_g(const float* b_ih, const float* b_hh, const float* lhid,
                          float* out, float* ws) {
    gates_body(blockIdx.x*256 + threadIdx.x, ws, b_ih, b_hh, lhid, out, ws);
}
__global__ void __launch_bounds__(256) k_attn_logh_g(const float* enc, const float* oW,
                                                     const float* out, float* ws) {
    int widx = threadIdx.x >> 6, lane = threadIdx.x & 63;
    if (blockIdx.x < 500) { logh_body(blockIdx.x*4 + widx, lane, oW, ws); return; }
    int blk = blockIdx.x - 500;
    attn_body(blk >> 4, (blk & 15)*4 + widx, lane, enc, (const float*)out, ws);
}
__global__ void k_reduce_g(float* out, float* ws) {
    __shared__ float s_a[256], s_b[256], s_c[64], s_m[2];
    reduce_body(blockIdx.x >> 2, blockIdx.x & 3, threadIdx.x, s_a, s_b, s_c, s_m, ws, out, ws);
}
__global__ void __launch_bounds__(256) k_ctx_g(const float* oW, const float* ob,
                                               float* out, float* ws) {
    int vt = blockIdx.x*4 + (threadIdx.x >> 6);
    ctx_body(vt, threadIdx.x & 63, oW, ob, ws, out, ws);
}
__global__ void k_lsenorm_g(float* out, float* ws) {
    __shared__ float s_a[256], s_b[256];
    lsenorm_body(blockIdx.x >> 3, blockIdx.x & 7, threadIdx.x, s_a, s_b, ws, out);
}

extern "C" void kernel_launch(void* const* d_in, const int* in_sizes, int n_in,
                              void* d_out, int out_size, void* d_ws, size_t ws_size,
                              hipStream_t stream) {
    const int*   wi   = (const int*)d_in[0];
    const float* lctx = (const float*)d_in[1];
    const float* lhid = (const float*)d_in[2];
    const float* enc  = (const float*)d_in[3];
    const float* emb  = (const float*)d_in[4];
    const float* w_ih = (const float*)d_in[5];
    const float* w_hh = (const float*)d_in[6];
    const float* b_ih = (const float*)d_in[7];
    const float* b_hh = (const float*)d_in[8];
    const float* oW   = (const float*)d_in[9];
    const float* ob   = (const float*)d_in[10];
    float* out = (float*)d_out;
    float* ws  = (float*)d_ws;

    void* args[] = { (void*)&wi, (void*)&lctx, (void*)&lhid, (void*)&enc, (void*)&emb,
                     (void*)&w_ih, (void*)&w_hh, (void*)&b_ih, (void*)&b_hh,
                     (void*)&oW, (void*)&ob, (void*)&out, (void*)&ws };
    hipError_t e = hipLaunchCooperativeKernel((const void*)k_mega, dim3(768), dim3(256),
                                              args, 0, stream);
    if (e != hipSuccess) {
        // fallback: r8 multi-kernel sequence (best known-good)
        hipLaunchKernelGGL(k_prep_g,      dim3(64),   dim3(256), 0, stream, wi, lctx, lhid, emb, ws);
        hipLaunchKernelGGL(k_gru_g,       dim3(576),  dim3(256), 0, stream, w_ih, w_hh, ws);
        hipLaunchKernelGGL(k_gates_g,     dim3(256),  dim3(256), 0, stream, b_ih, b_hh, lhid, out, ws);
        hipLaunchKernelGGL(k_attn_logh_g, dim3(1524), dim3(256), 0, stream, enc, oW, out, ws);
        hipLaunchKernelGGL(k_reduce_g,    dim3(256),  dim3(256), 0, stream, out, ws);
        hipLaunchKernelGGL(k_ctx_g,       dim3(500),  dim3(256), 0, stream, oW, ob, out, ws);
        hipLaunchKernelGGL(k_lsenorm_g,   dim3(512),  dim3(256), 0, stream, out, ws);
    }
}

// Round 11
// 189.450 us; speedup vs baseline: 3.8791x; 3.8791x over previous
//
#include <hip/hip_runtime.h>
#include <math.h>

#define NV 32000
#define NE 1024
#define NH 1024
#define NS 1024
#define NB 64

typedef __attribute__((ext_vector_type(4))) float f32x4;
typedef __attribute__((ext_vector_type(8))) short bf16x8;

// d_out layout (floats): output(B,V) | context(B,H) | hidden(1,B,H) | attn(B,1,S)
#define OUT_CTX   (NB*NV)
#define OUT_HID   (NB*NV + NB*NH)
#define OUT_ATTN  (NB*NV + 2*NB*NH)

// workspace layout (float offsets)
#define WS_XA   0                          // ushort[64][2048] x0 bf16, FRAGMENT-ORDERED
#define WS_HA   (WS_XA + 65536)            // ushort[64][1024] h_prev bf16, FRAGMENT-ORDERED
#define WS_PG   (WS_HA + 32768)            // f32 [12][3072][64] GRU partials
#define WS_E    (WS_PG + 12*3072*64)       // f32 [64][1024] raw energies
#define WS_PCTX (WS_E + NB*NS)             // f32 [64][64][1024] attn ctx partials (b, g, h)
#define WS_ML   (WS_PCTX + 64*64*1024)     // f32 [64][64][2]  (m, l) per (b, g)
#define WS_LA   (WS_ML + 8192)             // ushort[64][2048] concat(h,ctx) bf16, FRAGMENT-ORDERED
#define WS_ML2  (WS_LA + 65536)            // f32 [64][2048][2] logits chunk (m,l) per (row, vt)
#define WS_LSE  (WS_ML2 + 64*2048*2)       // f32 [64] lse per row
#define WS_P    (WS_LSE + 64)              // f32 [2000][1024] logits h-half partials, tile-blocked

// fragment-ordered offset (in shorts) for a [64][K] bf16 activation matrix:
// off(row,k) = ((k>>5)*4 + ((k>>3)&3))*512 + row*8 + (k&7)
// GEMM wave reads: base = A + kg*512 + col*8;  af(m,k0) = base + (k0>>5)*2048 + m*128

__device__ inline unsigned short f2bf(float f) {
    unsigned u = __builtin_bit_cast(unsigned, f);
    u += 0x7fffu + ((u >> 16) & 1u);   // RNE
    return (unsigned short)(u >> 16);
}

__device__ inline bf16x8 cvt8(float4 a, float4 b) {
    bf16x8 r;
    r[0] = (short)f2bf(a.x); r[1] = (short)f2bf(a.y);
    r[2] = (short)f2bf(a.z); r[3] = (short)f2bf(a.w);
    r[4] = (short)f2bf(b.x); r[5] = (short)f2bf(b.y);
    r[6] = (short)f2bf(b.z); r[7] = (short)f2bf(b.w);
    return r;
}

__device__ inline void store_bf4(unsigned short* p, float4 v) {
    ushort4 u = make_ushort4(f2bf(v.x), f2bf(v.y), f2bf(v.z), f2bf(v.w));
    *(ushort4*)p = u;
}

// ---------------- prep: x0 = concat(emb, lctx), h_prev -> bf16, fragment-ordered ----------------
__global__ void k_prep(const int* __restrict__ wi, const float* __restrict__ lctx,
                       const float* __restrict__ lhid, const float* __restrict__ emb,
                       float* __restrict__ ws) {
    int b = blockIdx.x, t = threadIdx.x;           // 64 x 256
    unsigned short* XA = (unsigned short*)(ws + WS_XA);
    unsigned short* HA = (unsigned short*)(ws + WS_HA);
    long row = wi[b];
    float4 e4 = ((const float4*)(emb + row*NE))[t];
    float4 c4 = ((const float4*)(lctx + (long)b*NH))[t];
    float4 h4 = ((const float4*)(lhid + (long)b*NH))[t];
    int o1 = ((t>>3)*4 + ((t>>1)&3))*512 + b*8 + 4*(t&1);
    int o2 = ((32 + (t>>3))*4 + ((t>>1)&3))*512 + b*8 + 4*(t&1);
    store_bf4(XA + o1, e4);
    store_bf4(XA + o2, c4);
    store_bf4(HA + o1, h4);
}

// ---------------- GRU GEMM via MFMA: partials [12][3072][64], K-chunks of 256 ----------------
__global__ void __launch_bounds__(256) k_gru_mfma(const float* __restrict__ w_ih,
                                                  const float* __restrict__ w_hh,
                                                  float* __restrict__ ws) {
    int wave = blockIdx.x*4 + (threadIdx.x >> 6);   // 2304 waves (576 blocks)
    int lane = threadIdx.x & 63;
    int c = wave % 12, ntile = wave / 12;           // 192 n-tiles
    int n0 = ntile * 16;
    int col = lane & 15, kg = lane >> 4;
    const unsigned short* XA = (const unsigned short*)(ws + WS_XA);
    const unsigned short* HA = (const unsigned short*)(ws + WS_HA);
    const float* Wp; const unsigned short* Af; int ld, kbase;
    if (c < 8) { Wp = w_ih; Af = XA; ld = 2048; kbase = c*256; }
    else       { Wp = w_hh; Af = HA; ld = 1024; kbase = (c-8)*256; }
    const float* wrow = Wp + (long)(n0 + col)*ld + kbase + kg*8;
    const unsigned short* ap = Af + (kbase>>5)*2048 + kg*512 + col*8;
    f32x4 acc[4];
    #pragma unroll
    for (int m = 0; m < 4; m++) acc[m] = (f32x4){0.f,0.f,0.f,0.f};
    #pragma unroll 4
    for (int k0 = 0; k0 < 256; k0 += 32) {
        float4 wa = *(const float4*)(wrow + k0);
        float4 wb = *(const float4*)(wrow + k0 + 4);
        bf16x8 bfv = cvt8(wa, wb);
        const unsigned short* a0 = ap + (k0>>5)*2048;
        #pragma unroll
        for (int m = 0; m < 4; m++) {
            bf16x8 af = *(const bf16x8*)(a0 + m*128);
            acc[m] = __builtin_amdgcn_mfma_f32_16x16x32_bf16(af, bfv, acc[m], 0, 0, 0);
        }
    }
    float* pg = ws + WS_PG + ((long)c*3072 + n0 + col)*64;
    #pragma unroll
    for (int m = 0; m < 4; m++)
        #pragma unroll
        for (int j = 0; j < 4; j++)
            pg[m*16 + kg*4 + j] = acc[m][j];
}

// ---------------- GRU gates ----------------
__global__ void k_gates(const float* __restrict__ wsc, const float* __restrict__ b_ih,
                        const float* __restrict__ b_hh, const float* __restrict__ lhid,
                        float* __restrict__ out, float* __restrict__ ws) {
    int g = blockIdx.x*256 + threadIdx.x;  // 65536 threads
    int b = g & 63, i = g >> 6;
    float gir=0.f, giz=0.f, gin=0.f, ghr=0.f, ghz=0.f, ghn=0.f;
    #pragma unroll
    for (int c = 0; c < 8; c++) {
        long base = WS_PG + (long)c*3072*64;
        gir += wsc[base + ((long)(0*NH + i))*64 + b];
        giz += wsc[base + ((long)(1*NH + i))*64 + b];
        gin += wsc[base + ((long)(2*NH + i))*64 + b];
    }
    #pragma unroll
    for (int c = 8; c < 12; c++) {
        long base = WS_PG + (long)c*3072*64;
        ghr += wsc[base + ((long)(0*NH + i))*64 + b];
        ghz += wsc[base + ((long)(1*NH + i))*64 + b];
        ghn += wsc[base + ((long)(2*NH + i))*64 + b];
    }
    gir += b_ih[i];        ghr += b_hh[i];
    giz += b_ih[NH + i];   ghz += b_hh[NH + i];
    gin += b_ih[2*NH + i]; ghn += b_hh[2*NH + i];
    float r = 1.f / (1.f + expf(-(gir + ghr)));
    float z = 1.f / (1.f + expf(-(giz + ghz)));
    float n = tanhf(gin + r*ghn);
    float hp = lhid[(long)b*NH + i];
    float h = (1.f - z)*n + z*hp;
    out[OUT_HID + (long)b*NH + i] = h;
    ((unsigned short*)(ws + WS_LA))[((i>>5)*4 + ((i>>3)&3))*512 + b*8 + (i&7)] = f2bf(h);
}

// ---------------- fused: attention (blocks 0..1023, LPT-first) + logits h-half (1024..1523) ----------------
__global__ void __launch_bounds__(256) k_attn_logh(const float* __restrict__ enc,
                                                   const float* __restrict__ oW,
                                                   const float* __restrict__ out,
                                                   float* __restrict__ ws) {
    int widx = threadIdx.x >> 6, lane = threadIdx.x & 63;
    if (blockIdx.x >= 1024) {
        // ---- logits h-half: vt = (blockIdx.x-1024)*4 + widx, K = 0..1023 ----
        int vt = (blockIdx.x - 1024)*4 + widx;
        int v0 = vt * 16;
        int col = lane & 15, kg = lane >> 4;
        const unsigned short* LA = (const unsigned short*)(ws + WS_LA);
        const float* wrow = oW + (long)(v0 + col)*2048 + kg*8;
        const unsigned short* ap = LA + kg*512 + col*8;
        f32x4 acc[4];
        #pragma unroll
        for (int m = 0; m < 4; m++) acc[m] = (f32x4){0.f,0.f,0.f,0.f};
        #pragma unroll 4
        for (int k0 = 0; k0 < 1024; k0 += 32) {
            float4 wa = *(const float4*)(wrow + k0);
            float4 wb = *(const float4*)(wrow + k0 + 4);
            bf16x8 bfv = cvt8(wa, wb);
            const unsigned short* a0 = ap + (k0>>5)*2048;
            #pragma unroll
            for (int m = 0; m < 4; m++) {
                bf16x8 af = *(const bf16x8*)(a0 + m*128);
                acc[m] = __builtin_amdgcn_mfma_f32_16x16x32_bf16(af, bfv, acc[m], 0, 0, 0);
            }
        }
        float* P = ws + WS_P + (long)vt*1024;
        #pragma unroll
        for (int m = 0; m < 4; m++)
            #pragma unroll
            for (int j = 0; j < 4; j++)
                P[(m*16 + kg*4 + j)*16 + col] = acc[m][j];
        return;
    }
    // ---- attention: blocks 0..1023 (longest stream dispatched first) ----
    int b = blockIdx.x >> 4;
    int g = (blockIdx.x & 15)*4 + widx;      // 0..63
    const float4* hr = (const float4*)(out + OUT_HID + (long)b*NH);
    float4 h0 = hr[lane], h1 = hr[64+lane], h2 = hr[128+lane], h3 = hr[192+lane];
    float m = -1e30f, l = 0.f;
    float4 c0 = make_float4(0,0,0,0), c1 = c0, c2 = c0, c3 = c0;
    const float4* vp = (const float4*)(enc + ((long)(g*16)*NB + b)*NH);
    const long sstr = (long)NB*NH/4;         // float4 stride between s
    float4 a0 = vp[lane], a1 = vp[64+lane], a2 = vp[128+lane], a3 = vp[192+lane];
    #pragma unroll
    for (int si = 0; si < 16; si++) {
        float4 n0 = a0, n1 = a1, n2 = a2, n3 = a3;
        if (si < 15) {
            const float4* np = vp + (long)(si+1)*sstr;
            n0 = np[lane]; n1 = np[64+lane]; n2 = np[128+lane]; n3 = np[192+lane];
        }
        float d = a0.x*h0.x + a0.y*h0.y + a0.z*h0.z + a0.w*h0.w
                + a1.x*h1.x + a1.y*h1.y + a1.z*h1.z + a1.w*h1.w
                + a2.x*h2.x + a2.y*h2.y + a2.z*h2.z + a2.w*h2.w
                + a3.x*h3.x + a3.y*h3.y + a3.z*h3.z + a3.w*h3.w;
        #pragma unroll
        for (int o = 32; o > 0; o >>= 1) d += __shfl_xor(d, o);
        if (lane == 0) ws[WS_E + (long)b*NS + g*16 + si] = d;
        // defer-max: rescale only when d exceeds running max by > 8 (wave-uniform branch)
        if (d > m + 8.f) {
            float coef = expf(m - d);       // m=-1e30 first time -> coef = 0
            l *= coef;
            c0.x *= coef; c0.y *= coef; c0.z *= coef; c0.w *= coef;
            c1.x *= coef; c1.y *= coef; c1.z *= coef; c1.w *= coef;
            c2.x *= coef; c2.y *= coef; c2.z *= coef; c2.w *= coef;
            c3.x *= coef; c3.y *= coef; c3.z *= coef; c3.w *= coef;
            m = d;
        }
        float p = expf(d - m);               // bounded by e^8
        l += p;
        c0.x += p*a0.x; c0.y += p*a0.y; c0.z += p*a0.z; c0.w += p*a0.w;
        c1.x += p*a1.x; c1.y += p*a1.y; c1.z += p*a1.z; c1.w += p*a1.w;
        c2.x += p*a2.x; c2.y += p*a2.y; c2.z += p*a2.z; c2.w += p*a2.w;
        c3.x += p*a3.x; c3.y += p*a3.y; c3.z += p*a3.z; c3.w += p*a3.w;
        a0 = n0; a1 = n1; a2 = n2; a3 = n3;
    }
    float* pc = ws + WS_PCTX + ((long)b*64 + g)*1024;
    *(float4*)(pc + 0*256 + lane*4) = c0;
    *(float4*)(pc + 1*256 + lane*4) = c1;
    *(float4*)(pc + 2*256 + lane*4) = c2;
    *(float4*)(pc + 3*256 + lane*4) = c3;
    if (lane == 0) {
        ws[WS_ML + ((long)b*64 + g)*2]     = m;
        ws[WS_ML + ((long)b*64 + g)*2 + 1] = l;
    }
}

// ---------------- attn reduce (wide): 256 blocks = (b, quarter) ----------------
__global__ void k_attn_reduce(const float* __restrict__ wsc, float* __restrict__ out,
                              float* __restrict__ ws) {
    int b = blockIdx.x >> 2, q = blockIdx.x & 3;   // 256 blocks x 256 threads
    int t = threadIdx.x;
    __shared__ float sm[64], sl[64], sc[64];
    __shared__ float sM, sinvL;
    if (t < 64) {
        sm[t] = wsc[WS_ML + ((long)b*64 + t)*2];
        sl[t] = wsc[WS_ML + ((long)b*64 + t)*2 + 1];
    }
    __syncthreads();
    if (t == 0) {
        float M = -1e30f;
        for (int g = 0; g < 64; g++) M = fmaxf(M, sm[g]);
        float L = 0.f;
        for (int g = 0; g < 64; g++) L += sl[g]*expf(sm[g] - M);
        sM = M; sinvL = 1.f/L;
    }
    __syncthreads();
    float M = sM, invL = sinvL;
    if (t < 64) sc[t] = expf(sm[t] - M);
    __syncthreads();
    int h = q*256 + t;
    float acc = 0.f;
    #pragma unroll 8
    for (int g = 0; g < 64; g++)
        acc += sc[g] * wsc[WS_PCTX + ((long)b*64 + g)*1024 + h];
    float ctx = acc * invL;
    out[OUT_CTX + (long)b*NH + h] = ctx;
    int k = 1024 + h;
    ((unsigned short*)(ws + WS_LA))[((k>>5)*4 + ((k>>3)&3))*512 + b*8 + (k&7)] = f2bf(ctx);
    int s = q*256 + t;
    float e = wsc[WS_E + (long)b*NS + s];
    out[OUT_ATTN + (long)b*NS + s] = expf(e - M)*invL;
}

// ---------------- logits ctx-half + partial + bias -> out, chunk (m,l) ----------------
__global__ void __launch_bounds__(256) k_logits_ctx(const float* __restrict__ oW,
                                                    const float* __restrict__ ob,
                                                    const float* __restrict__ wsc,
                                                    float* __restrict__ out,
                                                    float* __restrict__ ws) {
    int widx = threadIdx.x >> 6, lane = threadIdx.x & 63;
    int vt = blockIdx.x*4 + widx;           // 0..1999
    int v0 = vt * 16;
    int col = lane & 15, kg = lane >> 4;
    const unsigned short* LA = (const unsigned short*)(wsc + WS_LA);
    const float* wrow = oW + (long)(v0 + col)*2048 + 1024 + kg*8;
    const unsigned short* ap = LA + 32*2048 + kg*512 + col*8;   // k-base 1024
    f32x4 acc[4];
    #pragma unroll
    for (int m = 0; m < 4; m++) acc[m] = (f32x4){0.f,0.f,0.f,0.f};
    #pragma unroll 4
    for (int k0 = 0; k0 < 1024; k0 += 32) {
        float4 wa = *(const float4*)(wrow + k0);
        float4 wb = *(const float4*)(wrow + k0 + 4);
        bf16x8 bfv = cvt8(wa, wb);
        const unsigned short* a0 = ap + (k0>>5)*2048;
        #pragma unroll
        for (int m = 0; m < 4; m++) {
            bf16x8 af = *(const bf16x8*)(a0 + m*128);
            acc[m] = __builtin_amdgcn_mfma_f32_16x16x32_bf16(af, bfv, acc[m], 0, 0, 0);
        }
    }
    const float* P = wsc + WS_P + (long)vt*1024;
    float bias = ob[v0 + col];
    #pragma unroll
    for (int m = 0; m < 4; m++) {
        #pragma unroll
        for (int j = 0; j < 4; j++) {
            int row = m*16 + kg*4 + j;
            float v = acc[m][j] + P[row*16 + col] + bias;
            out[(long)row*NV + v0 + col] = v;
            float mx = v;
            mx = fmaxf(mx, __shfl_xor(mx, 1));
            mx = fmaxf(mx, __shfl_xor(mx, 2));
            mx = fmaxf(mx, __shfl_xor(mx, 4));
            mx = fmaxf(mx, __shfl_xor(mx, 8));
            float p = expf(v - mx);
            p += __shfl_xor(p, 1);
            p += __shfl_xor(p, 2);
            p += __shfl_xor(p, 4);
            p += __shfl_xor(p, 8);
            if (col == 0)
                *(float2*)(ws + WS_ML2 + ((long)row*2048 + vt)*2) = make_float2(mx, p);
        }
    }
}

// ---------------- fused lse + normalize: 512 blocks = (b, oct) ----------------
__global__ void __launch_bounds__(256) k_lsenorm(const float* __restrict__ wsc,
                                                 float* __restrict__ out) {
    int b = blockIdx.x >> 3, oct = blockIdx.x & 7;  // 512 blocks x 256 threads
    int t = threadIdx.x;
    __shared__ float sm_[256], sl_[256];
    const float2* ml = (const float2*)(wsc + WS_ML2 + (long)b*4096);
    float m = -1e30f, l = 0.f;
    for (int c = t; c < 2000; c += 256) {
        float2 v = ml[c];
        float mn = fmaxf(m, v.x);
        l = l*expf(m - mn) + v.y*expf(v.x - mn);
        m = mn;
    }
    sm_[t] = m; sl_[t] = l; __syncthreads();
    for (int o = 128; o > 0; o >>= 1) {
        if (t < o) {
            float m2 = sm_[t+o], l2 = sl_[t+o];
            float mn = fmaxf(sm_[t], m2);
            sl_[t] = sl_[t]*expf(sm_[t] - mn) + l2*expf(m2 - mn);
            sm_[t] = mn;
        }
        __syncthreads();
    }
    float lse = sm_[0] + logf(sl_[0]);
    float4* row4 = (float4*)(out + (long)b*NV + oct*4000);
    #pragma unroll
    for (int j = 0; j < 4; j++) {
        int idx = t + j*256;
        if (idx < 1000) {
            float4 v = row4[idx];
            row4[idx] = make_float4(v.x-lse, v.y-lse, v.z-lse, v.w-lse);
        }
    }
}

extern "C" void kernel_launch(void* const* d_in, const int* in_sizes, int n_in,
                              void* d_out, int out_size, void* d_ws, size_t ws_size,
                              hipStream_t stream) {
    const int*   wi   = (const int*)d_in[0];
    const float* lctx = (const float*)d_in[1];
    const float* lhid = (const float*)d_in[2];
    const float* enc  = (const float*)d_in[3];
    const float* emb  = (const float*)d_in[4];
    const float* w_ih = (const float*)d_in[5];
    const float* w_hh = (const float*)d_in[6];
    const float* b_ih = (const float*)d_in[7];
    const float* b_hh = (const float*)d_in[8];
    const float* oW   = (const float*)d_in[9];
    const float* ob   = (const float*)d_in[10];
    float* out = (float*)d_out;
    float* ws  = (float*)d_ws;

    hipLaunchKernelGGL(k_prep,        dim3(64),   dim3(256), 0, stream, wi, lctx, lhid, emb, ws);
    hipLaunchKernelGGL(k_gru_mfma,    dim3(576),  dim3(256), 0, stream, w_ih, w_hh, ws);
    hipLaunchKernelGGL(k_gates,       dim3(256),  dim3(256), 0, stream, ws, b_ih, b_hh, lhid, out, ws);
    hipLaunchKernelGGL(k_attn_logh,   dim3(1524), dim3(256), 0, stream, enc, oW, out, ws);
    hipLaunchKernelGGL(k_attn_reduce, dim3(256),  dim3(256), 0, stream, ws, out, ws);
    hipLaunchKernelGGL(k_logits_ctx,  dim3(500),  dim3(256), 0, stream, oW, ob, ws, out, ws);
    hipLaunchKernelGGL(k_lsenorm,     dim3(512),  dim3(256), 0, stream, ws, out);
}

// Round 13
// 180.598 us; speedup vs baseline: 4.0692x; 1.0490x over previous
//
#include <hip/hip_runtime.h>
#include <math.h>

#define NV 32000
#define NE 1024
#define NH 1024
#define NS 1024
#define NB 64

typedef __attribute__((ext_vector_type(4))) float f32x4;
typedef __attribute__((ext_vector_type(8))) short bf16x8;

// d_out layout (floats): output(B,V) | context(B,H) | hidden(1,B,H) | attn(B,1,S)
#define OUT_CTX   (NB*NV)
#define OUT_HID   (NB*NV + NB*NH)
#define OUT_ATTN  (NB*NV + 2*NB*NH)

// workspace layout (float offsets)
#define WS_XA   0                          // ushort[64][2048] x0 bf16, FRAGMENT-ORDERED
#define WS_HA   (WS_XA + 65536)            // ushort[64][1024] h_prev bf16, FRAGMENT-ORDERED
#define WS_PG   (WS_HA + 32768)            // f32 [12][3072][64] GRU partials
#define WS_E    (WS_PG + 12*3072*64)       // f32 [64][1024] raw energies
#define WS_PCTX (WS_E + NB*NS)             // f32 [64][64][1024] attn ctx partials (b, g, h)
#define WS_ML   (WS_PCTX + 64*64*1024)     // f32 [64][64][2]  (m, l) per (b, g)
#define WS_LA   (WS_ML + 8192)             // ushort[64][2048] concat(h,ctx) bf16, FRAGMENT-ORDERED
#define WS_ML2  (WS_LA + 65536)            // f32 [64][2048][2] logits chunk (m,l) per (row, vt)
#define WS_LSE  (WS_ML2 + 64*2048*2)       // f32 [64] lse per row
#define WS_P    (WS_LSE + 64)              // f32 [2000][1024] logits h-half partials, tile-blocked

// fragment-ordered offset (in shorts) for a [64][K] bf16 activation matrix:
// off(row,k) = ((k>>5)*4 + ((k>>3)&3))*512 + row*8 + (k&7)
// GEMM wave reads: base = A + kg*512 + col*8;  af(m,k0) = base + (k0>>5)*2048 + m*128

__device__ inline unsigned short f2bf(float f) {
    unsigned u = __builtin_bit_cast(unsigned, f);
    u += 0x7fffu + ((u >> 16) & 1u);   // RNE
    return (unsigned short)(u >> 16);
}

__device__ inline bf16x8 cvt8(float4 a, float4 b) {
    bf16x8 r;
    r[0] = (short)f2bf(a.x); r[1] = (short)f2bf(a.y);
    r[2] = (short)f2bf(a.z); r[3] = (short)f2bf(a.w);
    r[4] = (short)f2bf(b.x); r[5] = (short)f2bf(b.y);
    r[6] = (short)f2bf(b.z); r[7] = (short)f2bf(b.w);
    return r;
}

__device__ inline void store_bf4(unsigned short* p, float4 v) {
    ushort4 u = make_ushort4(f2bf(v.x), f2bf(v.y), f2bf(v.z), f2bf(v.w));
    *(ushort4*)p = u;
}

// non-temporal float4 load via ext-vector type (builtin requires real vector type)
__device__ inline float4 ntload4(const float* p) {
    f32x4 v = __builtin_nontemporal_load((const f32x4*)p);
    return make_float4(v[0], v[1], v[2], v[3]);
}

// ---------------- prep: x0 = concat(emb, lctx), h_prev -> bf16, fragment-ordered ----------------
__global__ void k_prep(const int* __restrict__ wi, const float* __restrict__ lctx,
                       const float* __restrict__ lhid, const float* __restrict__ emb,
                       float* __restrict__ ws) {
    int b = blockIdx.x, t = threadIdx.x;           // 64 x 256
    unsigned short* XA = (unsigned short*)(ws + WS_XA);
    unsigned short* HA = (unsigned short*)(ws + WS_HA);
    long row = wi[b];
    float4 e4 = ((const float4*)(emb + row*NE))[t];
    float4 c4 = ((const float4*)(lctx + (long)b*NH))[t];
    float4 h4 = ((const float4*)(lhid + (long)b*NH))[t];
    int o1 = ((t>>3)*4 + ((t>>1)&3))*512 + b*8 + 4*(t&1);
    int o2 = ((32 + (t>>3))*4 + ((t>>1)&3))*512 + b*8 + 4*(t&1);
    store_bf4(XA + o1, e4);
    store_bf4(XA + o2, c4);
    store_bf4(HA + o1, h4);
}

// ---------------- GRU GEMM via MFMA: partials [12][3072][64], K-chunks of 256 ----------------
__global__ void __launch_bounds__(256) k_gru_mfma(const float* __restrict__ w_ih,
                                                  const float* __restrict__ w_hh,
                                                  float* __restrict__ ws) {
    int wave = blockIdx.x*4 + (threadIdx.x >> 6);   // 2304 waves (576 blocks)
    int lane = threadIdx.x & 63;
    int c = wave % 12, ntile = wave / 12;           // 192 n-tiles
    int n0 = ntile * 16;
    int col = lane & 15, kg = lane >> 4;
    const unsigned short* XA = (const unsigned short*)(ws + WS_XA);
    const unsigned short* HA = (const unsigned short*)(ws + WS_HA);
    const float* Wp; const unsigned short* Af; int ld, kbase;
    if (c < 8) { Wp = w_ih; Af = XA; ld = 2048; kbase = c*256; }
    else       { Wp = w_hh; Af = HA; ld = 1024; kbase = (c-8)*256; }
    const float* wrow = Wp + (long)(n0 + col)*ld + kbase + kg*8;
    const unsigned short* ap = Af + (kbase>>5)*2048 + kg*512 + col*8;
    f32x4 acc[4];
    #pragma unroll
    for (int m = 0; m < 4; m++) acc[m] = (f32x4){0.f,0.f,0.f,0.f};
    #pragma unroll 4
    for (int k0 = 0; k0 < 256; k0 += 32) {
        float4 wa = ntload4(wrow + k0);
        float4 wb = ntload4(wrow + k0 + 4);
        bf16x8 bfv = cvt8(wa, wb);
        const unsigned short* a0 = ap + (k0>>5)*2048;
        #pragma unroll
        for (int m = 0; m < 4; m++) {
            bf16x8 af = *(const bf16x8*)(a0 + m*128);
            acc[m] = __builtin_amdgcn_mfma_f32_16x16x32_bf16(af, bfv, acc[m], 0, 0, 0);
        }
    }
    float* pg = ws + WS_PG + ((long)c*3072 + n0 + col)*64;
    #pragma unroll
    for (int m = 0; m < 4; m++)
        #pragma unroll
        for (int j = 0; j < 4; j++)
            pg[m*16 + kg*4 + j] = acc[m][j];
}

// ---------------- GRU gates ----------------
__global__ void k_gates(const float* __restrict__ wsc, const float* __restrict__ b_ih,
                        const float* __restrict__ b_hh, const float* __restrict__ lhid,
                        float* __restrict__ out, float* __restrict__ ws) {
    int g = blockIdx.x*256 + threadIdx.x;  // 65536 threads
    int b = g & 63, i = g >> 6;
    float gir=0.f, giz=0.f, gin=0.f, ghr=0.f, ghz=0.f, ghn=0.f;
    #pragma unroll
    for (int c = 0; c < 8; c++) {
        long base = WS_PG + (long)c*3072*64;
        gir += wsc[base + ((long)(0*NH + i))*64 + b];
        giz += wsc[base + ((long)(1*NH + i))*64 + b];
        gin += wsc[base + ((long)(2*NH + i))*64 + b];
    }
    #pragma unroll
    for (int c = 8; c < 12; c++) {
        long base = WS_PG + (long)c*3072*64;
        ghr += wsc[base + ((long)(0*NH + i))*64 + b];
        ghz += wsc[base + ((long)(1*NH + i))*64 + b];
        ghn += wsc[base + ((long)(2*NH + i))*64 + b];
    }
    gir += b_ih[i];        ghr += b_hh[i];
    giz += b_ih[NH + i];   ghz += b_hh[NH + i];
    gin += b_ih[2*NH + i]; ghn += b_hh[2*NH + i];
    float r = 1.f / (1.f + expf(-(gir + ghr)));
    float z = 1.f / (1.f + expf(-(giz + ghz)));
    float n = tanhf(gin + r*ghn);
    float hp = lhid[(long)b*NH + i];
    float h = (1.f - z)*n + z*hp;
    out[OUT_HID + (long)b*NH + i] = h;
    ((unsigned short*)(ws + WS_LA))[((i>>5)*4 + ((i>>3)&3))*512 + b*8 + (i&7)] = f2bf(h);
}

// ---------------- fused: logits h-half (blocks 0..499) + attention (500..1523), r8 order ----------------
__global__ void __launch_bounds__(256) k_attn_logh(const float* __restrict__ enc,
                                                   const float* __restrict__ oW,
                                                   const float* __restrict__ out,
                                                   float* __restrict__ ws) {
    int widx = threadIdx.x >> 6, lane = threadIdx.x & 63;
    if (blockIdx.x < 500) {
        // ---- logits h-half: vt = blockIdx.x*4 + widx, K = 0..1023 ----
        int vt = blockIdx.x*4 + widx;
        int v0 = vt * 16;
        int col = lane & 15, kg = lane >> 4;
        const unsigned short* LA = (const unsigned short*)(ws + WS_LA);
        const float* wrow = oW + (long)(v0 + col)*2048 + kg*8;
        const unsigned short* ap = LA + kg*512 + col*8;
        f32x4 acc[4];
        #pragma unroll
        for (int m = 0; m < 4; m++) acc[m] = (f32x4){0.f,0.f,0.f,0.f};
        #pragma unroll 4
        for (int k0 = 0; k0 < 1024; k0 += 32) {
            float4 wa = ntload4(wrow + k0);
            float4 wb = ntload4(wrow + k0 + 4);
            bf16x8 bfv = cvt8(wa, wb);
            const unsigned short* a0 = ap + (k0>>5)*2048;
            #pragma unroll
            for (int m = 0; m < 4; m++) {
                bf16x8 af = *(const bf16x8*)(a0 + m*128);
                acc[m] = __builtin_amdgcn_mfma_f32_16x16x32_bf16(af, bfv, acc[m], 0, 0, 0);
            }
        }
        float* P = ws + WS_P + (long)vt*1024;
        #pragma unroll
        for (int m = 0; m < 4; m++)
            #pragma unroll
            for (int j = 0; j < 4; j++)
                P[(m*16 + kg*4 + j)*16 + col] = acc[m][j];
        return;
    }
    // ---- attention: blocks 500..1523 ----
    int blk = blockIdx.x - 500;
    int b = blk >> 4;
    int g = (blk & 15)*4 + widx;             // 0..63
    const float4* hr = (const float4*)(out + OUT_HID + (long)b*NH);
    float4 h0 = hr[lane], h1 = hr[64+lane], h2 = hr[128+lane], h3 = hr[192+lane];
    float m = -1e30f, l = 0.f;
    float4 c0 = make_float4(0,0,0,0), c1 = c0, c2 = c0, c3 = c0;
    const float* vb = enc + ((long)(g*16)*NB + b)*NH;
    const long sstr = (long)NB*NH;           // float stride between s
    float4 a0 = ntload4(vb + lane*4), a1 = ntload4(vb + 256 + lane*4),
           a2 = ntload4(vb + 512 + lane*4), a3 = ntload4(vb + 768 + lane*4);
    #pragma unroll
    for (int si = 0; si < 16; si++) {
        float4 n0 = a0, n1 = a1, n2 = a2, n3 = a3;
        if (si < 15) {
            const float* np = vb + (long)(si+1)*sstr;
            n0 = ntload4(np + lane*4); n1 = ntload4(np + 256 + lane*4);
            n2 = ntload4(np + 512 + lane*4); n3 = ntload4(np + 768 + lane*4);
        }
        float d = a0.x*h0.x + a0.y*h0.y + a0.z*h0.z + a0.w*h0.w
                + a1.x*h1.x + a1.y*h1.y + a1.z*h1.z + a1.w*h1.w
                + a2.x*h2.x + a2.y*h2.y + a2.z*h2.z + a2.w*h2.w
                + a3.x*h3.x + a3.y*h3.y + a3.z*h3.z + a3.w*h3.w;
        #pragma unroll
        for (int o = 32; o > 0; o >>= 1) d += __shfl_xor(d, o);
        if (lane == 0) ws[WS_E + (long)b*NS + g*16 + si] = d;
        // defer-max: rescale only when d exceeds running max by > 8 (wave-uniform branch)
        if (d > m + 8.f) {
            float coef = expf(m - d);       // m=-1e30 first time -> coef = 0
            l *= coef;
            c0.x *= coef; c0.y *= coef; c0.z *= coef; c0.w *= coef;
            c1.x *= coef; c1.y *= coef; c1.z *= coef; c1.w *= coef;
            c2.x *= coef; c2.y *= coef; c2.z *= coef; c2.w *= coef;
            c3.x *= coef; c3.y *= coef; c3.z *= coef; c3.w *= coef;
            m = d;
        }
        float p = expf(d - m);               // bounded by e^8
        l += p;
        c0.x += p*a0.x; c0.y += p*a0.y; c0.z += p*a0.z; c0.w += p*a0.w;
        c1.x += p*a1.x; c1.y += p*a1.y; c1.z += p*a1.z; c1.w += p*a1.w;
        c2.x += p*a2.x; c2.y += p*a2.y; c2.z += p*a2.z; c2.w += p*a2.w;
        c3.x += p*a3.x; c3.y += p*a3.y; c3.z += p*a3.z; c3.w += p*a3.w;
        a0 = n0; a1 = n1; a2 = n2; a3 = n3;
    }
    float* pc = ws + WS_PCTX + ((long)b*64 + g)*1024;
    *(float4*)(pc + 0*256 + lane*4) = c0;
    *(float4*)(pc + 1*256 + lane*4) = c1;
    *(float4*)(pc + 2*256 + lane*4) = c2;
    *(float4*)(pc + 3*256 + lane*4) = c3;
    if (lane == 0) {
        ws[WS_ML + ((long)b*64 + g)*2]     = m;
        ws[WS_ML + ((long)b*64 + g)*2 + 1] = l;
    }
}

// ---------------- attn reduce (wide): 256 blocks = (b, quarter) ----------------
__global__ void k_attn_reduce(const float* __restrict__ wsc, float* __restrict__ out,
                              float* __restrict__ ws) {
    int b = blockIdx.x >> 2, q = blockIdx.x & 3;   // 256 blocks x 256 threads
    int t = threadIdx.x;
    __shared__ float sm[64], sl[64], sc[64];
    __shared__ float sM, sinvL;
    if (t < 64) {
        sm[t] = wsc[WS_ML + ((long)b*64 + t)*2];
        sl[t] = wsc[WS_ML + ((long)b*64 + t)*2 + 1];
    }
    __syncthreads();
    if (t == 0) {
        float M = -1e30f;
        for (int g = 0; g < 64; g++) M = fmaxf(M, sm[g]);
        float L = 0.f;
        for (int g = 0; g < 64; g++) L += sl[g]*expf(sm[g] - M);
        sM = M; sinvL = 1.f/L;
    }
    __syncthreads();
    float M = sM, invL = sinvL;
    if (t < 64) sc[t] = expf(sm[t] - M);
    __syncthreads();
    int h = q*256 + t;
    float acc = 0.f;
    #pragma unroll 8
    for (int g = 0; g < 64; g++)
        acc += sc[g] * wsc[WS_PCTX + ((long)b*64 + g)*1024 + h];
    float ctx = acc * invL;
    out[OUT_CTX + (long)b*NH + h] = ctx;
    int k = 1024 + h;
    ((unsigned short*)(ws + WS_LA))[((k>>5)*4 + ((k>>3)&3))*512 + b*8 + (k&7)] = f2bf(ctx);
    int s = q*256 + t;
    float e = wsc[WS_E + (long)b*NS + s];
    out[OUT_ATTN + (long)b*NS + s] = expf(e - M)*invL;
}

// ---------------- logits ctx-half + partial + bias -> out, chunk (m,l) ----------------
__global__ void __launch_bounds__(256) k_logits_ctx(const float* __restrict__ oW,
                                                    const float* __restrict__ ob,
                                                    const float* __restrict__ wsc,
                                                    float* __restrict__ out,
                                                    float* __restrict__ ws) {
    int widx = threadIdx.x >> 6, lane = threadIdx.x & 63;
    int vt = blockIdx.x*4 + widx;           // 0..1999
    int v0 = vt * 16;
    int col = lane & 15, kg = lane >> 4;
    const unsigned short* LA = (const unsigned short*)(wsc + WS_LA);
    const float* wrow = oW + (long)(v0 + col)*2048 + 1024 + kg*8;
    const unsigned short* ap = LA + 32*2048 + kg*512 + col*8;   // k-base 1024
    f32x4 acc[4];
    #pragma unroll
    for (int m = 0; m < 4; m++) acc[m] = (f32x4){0.f,0.f,0.f,0.f};
    #pragma unroll 4
    for (int k0 = 0; k0 < 1024; k0 += 32) {
        float4 wa = ntload4(wrow + k0);
        float4 wb = ntload4(wrow + k0 + 4);
        bf16x8 bfv = cvt8(wa, wb);
        const unsigned short* a0 = ap + (k0>>5)*2048;
        #pragma unroll
        for (int m = 0; m < 4; m++) {
            bf16x8 af = *(const bf16x8*)(a0 + m*128);
            acc[m] = __builtin_amdgcn_mfma_f32_16x16x32_bf16(af, bfv, acc[m], 0, 0, 0);
        }
    }
    const float* P = wsc + WS_P + (long)vt*1024;
    float bias = ob[v0 + col];
    #pragma unroll
    for (int m = 0; m < 4; m++) {
        #pragma unroll
        for (int j = 0; j < 4; j++) {
            int row = m*16 + kg*4 + j;
            float v = acc[m][j] + P[row*16 + col] + bias;
            out[(long)row*NV + v0 + col] = v;
            float mx = v;
            mx = fmaxf(mx, __shfl_xor(mx, 1));
            mx = fmaxf(mx, __shfl_xor(mx, 2));
            mx = fmaxf(mx, __shfl_xor(mx, 4));
            mx = fmaxf(mx, __shfl_xor(mx, 8));
            float p = expf(v - mx);
            p += __shfl_xor(p, 1);
            p += __shfl_xor(p, 2);
            p += __shfl_xor(p, 4);
            p += __shfl_xor(p, 8);
            if (col == 0)
                *(float2*)(ws + WS_ML2 + ((long)row*2048 + vt)*2) = make_float2(mx, p);
        }
    }
}

// ---------------- fused lse + normalize: 512 blocks = (b, oct) ----------------
__global__ void __launch_bounds__(256) k_lsenorm(const float* __restrict__ wsc,
                                                 float* __restrict__ out) {
    int b = blockIdx.x >> 3, oct = blockIdx.x & 7;  // 512 blocks x 256 threads
    int t = threadIdx.x;
    __shared__ float sm_[256], sl_[256];
    const float2* ml = (const float2*)(wsc + WS_ML2 + (long)b*4096);
    float m = -1e30f, l = 0.f;
    for (int c = t; c < 2000; c += 256) {
        float2 v = ml[c];
        float mn = fmaxf(m, v.x);
        l = l*expf(m - mn) + v.y*expf(v.x - mn);
        m = mn;
    }
    sm_[t] = m; sl_[t] = l; __syncthreads();
    for (int o = 128; o > 0; o >>= 1) {
        if (t < o) {
            float m2 = sm_[t+o], l2 = sl_[t+o];
            float mn = fmaxf(sm_[t], m2);
            sl_[t] = sl_[t]*expf(sm_[t] - mn) + l2*expf(m2 - mn);
            sm_[t] = mn;
        }
        __syncthreads();
    }
    float lse = sm_[0] + logf(sl_[0]);
    float4* row4 = (float4*)(out + (long)b*NV + oct*4000);
    #pragma unroll
    for (int j = 0; j < 4; j++) {
        int idx = t + j*256;
        if (idx < 1000) {
            float4 v = row4[idx];
            row4[idx] = make_float4(v.x-lse, v.y-lse, v.z-lse, v.w-lse);
        }
    }
}

extern "C" void kernel_launch(void* const* d_in, const int* in_sizes, int n_in,
                              void* d_out, int out_size, void* d_ws, size_t ws_size,
                              hipStream_t stream) {
    const int*   wi   = (const int*)d_in[0];
    const float* lctx = (const float*)d_in[1];
    const float* lhid = (const float*)d_in[2];
    const float* enc  = (const float*)d_in[3];
    const float* emb  = (const float*)d_in[4];
    const float* w_ih = (const float*)d_in[5];
    const float* w_hh = (const float*)d_in[6];
    const float* b_ih = (const float*)d_in[7];
    const float* b_hh = (const float*)d_in[8];
    const float* oW   = (const float*)d_in[9];
    const float* ob   = (const float*)d_in[10];
    float* out = (float*)d_out;
    float* ws  = (float*)d_ws;

    hipLaunchKernelGGL(k_prep,        dim3(64),   dim3(256), 0, stream, wi, lctx, lhid, emb, ws);
    hipLaunchKernelGGL(k_gru_mfma,    dim3(576),  dim3(256), 0, stream, w_ih, w_hh, ws);
    hipLaunchKernelGGL(k_gates,       dim3(256),  dim3(256), 0, stream, ws, b_ih, b_hh, lhid, out, ws);
    hipLaunchKernelGGL(k_attn_logh,   dim3(1524), dim3(256), 0, stream, enc, oW, out, ws);
    hipLaunchKernelGGL(k_attn_reduce, dim3(256),  dim3(256), 0, stream, ws, out, ws);
    hipLaunchKernelGGL(k_logits_ctx,  dim3(500),  dim3(256), 0, stream, oW, ob, ws, out, ws);
    hipLaunchKernelGGL(k_lsenorm,     dim3(512),  dim3(256), 0, stream, ws, out);
}